// Round 11
// baseline (211.411 us; speedup 1.0000x reference)
//
#include <hip/hip_runtime.h>
#include <hip/hip_bf16.h>

#define E_    8
#define CIN_  256
#define COUT_ 256
#define NK    9
#define KTOT  2304      // CIN*9
#define IMGH  56
#define IMGW  56
#define HW    3136
#define NBATCH 32
#define PADW  58
#define PADHW 3364      // 58*58

typedef __attribute__((ext_vector_type(8))) __bf16 bf16x8;
typedef __attribute__((ext_vector_type(4))) float f32x4;
typedef unsigned int u32;

// async global->LDS, 16B per lane; LDS dest = wave-uniform base + lane*16
__device__ __forceinline__ void gld_lds16(const __bf16* g, __bf16* l) {
    __builtin_amdgcn_global_load_lds(
        (const __attribute__((address_space(1))) void*)(g),
        (__attribute__((address_space(3))) void*)(l), 16, 0, 0);
}

// ---- init: pooled = 0, xTp halo = 0 ----
__global__ __launch_bounds__(256) void init_kernel(__bf16* xTp, float* pooled) {
    const int tid0 = blockIdx.x * 256 + threadIdx.x;
    if (tid0 < NBATCH * CIN_) pooled[tid0] = 0.f;
    const int total = NBATCH * 228 * 128;     // halo u32 count
    u32* p = (u32*)xTp;
    for (int idx = tid0; idx < total; idx += gridDim.x * 256) {
        const int n  = idx / (228 * 128);
        const int r  = idx - n * (228 * 128);
        const int hp = r >> 7;
        const int cp = r & 127;
        int px;
        if (hp < 58)       px = hp;
        else if (hp < 116) px = 57 * PADW + (hp - 58);
        else if (hp < 172) px = (hp - 116 + 1) * PADW;
        else               px = (hp - 172 + 1) * PADW + 57;
        p[((size_t)(n * PADHW + px)) * 128 + cp] = 0u;
    }
}

// ---- transpose + pool ----
__global__ __launch_bounds__(256) void transpose_kernel(const float* __restrict__ x,
                                                        __bf16* __restrict__ xTp,
                                                        float* __restrict__ pooled) {
    __shared__ __bf16 t[64][66];
    const int px0 = blockIdx.x * 64;
    const int c0  = blockIdx.y * 64;
    const int n   = blockIdx.z;
    const int tid = threadIdx.x;
    {
        const int px_l = tid & 63;
        const int cb   = (tid >> 6) * 16;
        #pragma unroll
        for (int i = 0; i < 16; ++i) {
            const int cin_l = cb + i;
            t[cin_l][px_l] =
                (__bf16)x[((size_t)(n * CIN_ + c0 + cin_l)) * HW + px0 + px_l];
        }
    }
    __syncthreads();
    {
        const int cin_l = tid & 63;
        const int pb    = (tid >> 6) * 16;
        float s = 0.f;
        #pragma unroll
        for (int i = 0; i < 16; ++i) {
            const int px = px0 + pb + i;
            const int h  = px / IMGW;
            const int w  = px - h * IMGW;
            const __bf16 v = t[cin_l][pb + i];
            s += (float)v;
            xTp[((size_t)(n * PADHW + (h + 1) * PADW + (w + 1))) * CIN_ + c0 + cin_l] = v;
        }
        atomicAdd(&pooled[n * CIN_ + c0 + cin_l], s);
    }
}

// ---- gate ----
__global__ __launch_bounds__(256) void gate_kernel(const float* __restrict__ pooled,
                                                   const float* __restrict__ fc_w,
                                                   const float* __restrict__ fc_b,
                                                   float* __restrict__ gate) {
    const int t = threadIdx.x;
    const int n = t >> 3, e = t & 7;
    const float* pv = pooled + n * CIN_;
    const float* wv = fc_w + e * CIN_;
    float s = 0.f;
    for (int c = 0; c < CIN_; ++c) s += pv[c] * wv[c];
    s = s * (1.0f / HW) + fc_b[e];
    gate[t] = 1.0f / (1.0f + expf(-s));
}

// ---- mix: block = (cout, n-chunk of 8); experts in registers ----
__global__ __launch_bounds__(256) void mix_kernel(const float* __restrict__ weight,
                                                  const float* __restrict__ gate,
                                                  __bf16* __restrict__ wmix) {
    __shared__ float wstage[KTOT];
    __shared__ __bf16 tlds[KTOT];
    const int cout = blockIdx.x;
    const int n0   = blockIdx.y * 8;
    const int tid  = threadIdx.x;
    float wreg[E_][NK];
    for (int e = 0; e < E_; ++e) {
        const float* wp = weight + (size_t)(e * COUT_ + cout) * KTOT;
        #pragma unroll
        for (int i = 0; i < NK; ++i) wstage[tid + i * 256] = wp[tid + i * 256];
        __syncthreads();
        #pragma unroll
        for (int kk = 0; kk < NK; ++kk) wreg[e][kk] = wstage[tid * NK + kk];
        __syncthreads();
    }
    for (int n = n0; n < n0 + 8; ++n) {
        float g[E_];
        #pragma unroll
        for (int e = 0; e < E_; ++e) g[e] = gate[n * E_ + e];
        float acc[NK];
        #pragma unroll
        for (int kk = 0; kk < NK; ++kk) acc[kk] = 0.f;
        #pragma unroll
        for (int e = 0; e < E_; ++e)
            #pragma unroll
            for (int kk = 0; kk < NK; ++kk) acc[kk] += g[e] * wreg[e][kk];
        #pragma unroll
        for (int kk = 0; kk < NK; ++kk) tlds[kk * 256 + tid] = (__bf16)acc[kk];
        __syncthreads();
        u32* dst = (u32*)(wmix + ((size_t)(n * COUT_ + cout)) * KTOT);
        const u32* src = (const u32*)tlds;
        #pragma unroll
        for (int j = 0; j < 4; ++j) dst[tid + j * 256] = src[tid + j * 256];
        if (tid < 128) dst[tid + 1024] = src[tid + 1024];
        __syncthreads();
    }
}

// ---------------- implicit-GEMM conv: m201 8-phase-template port ----------
// BM=256 couts x BN=256 pixels (13 tiles: 12 full + 1 tail masked), BK=64,
// 512 threads = 8 waves as 2M x 4N (wave tile 128x64 = 8m x 4n frags).
// Per K-tile: 4 phases of 16 MFMA (quadrants by m-half x n-pair):
//   q0: ds A m0-3 (8) + B n01 (4); q1: ds B n23 (4); q2: ds A m4-7 (8); q3: 0.
// B resident in 32 VGPR across the tile. Staging: 4 chunks of 2 gld_lds per
// tile (q0: A-m03, q1: B-n01, q2: B-n23, q3: A-m47) targeting tile t+1;
// per phase: {stage 2; vmcnt(6); ds_reads; barrier; setprio1; MFMA; setprio0;
// barrier}. vmcnt(6)-after-issue => issues <= 3-phases-ago landed; every
// consumed chunk was staged >= 3 phases before its first read (lag proof in
// journal). No vmcnt(0) drain in the main loop (tile 35 peeled).
// LDS rows permuted so each chunk is 2 contiguous 8KB regions:
//   A: lds = (g&1)*128 + (g>>1)*64 + (row&63), g = row>>6
//   B: lds = (s&1)*128 + (s>>1)*32 + (row&31), s = row>>5
#define BM 256
#define BN 256

__global__ __launch_bounds__(512) void conv_kernel(const __bf16* __restrict__ xTp,
                                                   const __bf16* __restrict__ wmix,
                                                   float* __restrict__ out) {
    __shared__ __attribute__((aligned(16))) __bf16 At[2][BM * 64];  // 2x32 KB
    __shared__ __attribute__((aligned(16))) __bf16 Bt[2][BN * 64];  // 2x32 KB

    // bijective XCD swizzle (416 = 8*52); n-major within XCD
    const int bid = blockIdx.x;
    const int swz = (bid & 7) * 52 + (bid >> 3);
    const int n   = swz / 13;
    const int pt  = swz - n * 13;
    const int p0  = pt * BN;

    const int tid  = threadIdx.x;
    const int lane = tid & 63;
    const int wave = tid >> 6;                // 0..7
    const int wr   = wave >> 2;               // wave M-row 0..1
    const int wc   = wave & 3;                // wave N-col 0..3
    const int fr   = lane & 15;
    const int kg   = lane >> 4;
    const int fswz = fr & 7;

    const __bf16* wmixn = wmix + (size_t)n * COUT_ * KTOT;
    const __bf16* xTpn  = xTp + (size_t)n * PADHW * CIN_;

    // ---- staging source pointers (pre-swizzled slot) ----
    const int lr6 = tid >> 3;                 // lds row within 64-row region
    const int ssl = (tid & 7) ^ (lr6 & 7);    // pre-swizzled 16B slot
    const __bf16* aptr[4];                    // A lds regions i*64.. (i=0..3)
    #pragma unroll
    for (int i = 0; i < 4; ++i) {
        const int g = ((i & 1) << 1) | (i >> 1);      // inverse A row perm
        aptr[i] = wmixn + (size_t)(g * 64 + lr6) * KTOT + ssl * 8;
    }
    const __bf16* bptr[4];                    // B lds regions j*64..
    #pragma unroll
    for (int j = 0; j < 4; ++j) {
        const int lds_row = j * 64 + lr6;
        const int b32 = lds_row >> 5;
        const int s   = ((b32 & 3) << 1) | (b32 >> 2); // inverse B row perm
        int px = p0 + s * 32 + (lds_row & 31);
        if (px > HW - 1) px = HW - 1;                  // tail clamp
        const int h = px / IMGW;
        const int w = px - h * IMGW;
        bptr[j] = xTpn + (size_t)(h * PADW + w) * CIN_ + ssl * 8;
    }

    const f32x4 zero = {0.f, 0.f, 0.f, 0.f};
    f32x4 acc[8][4];
    #pragma unroll
    for (int i = 0; i < 8; ++i)
        #pragma unroll
        for (int j = 0; j < 4; ++j) acc[i][j] = zero;

    // frag LDS rows (element offsets = row*64 + slot*8)
    // A m-frag: lds_row = (m>>2)*128 + wr*64 + 16*(m&3) + fr
    // B n-frag: lds_row = (j>>1)*128 + wc*32 + (j&1)*16 + fr
    const int so0 = (kg ^ fswz) * 8;          // ks=0 slot offset
    const int so1 = ((4 + kg) ^ fswz) * 8;    // ks=1
    const int arow0 = wr * 64 + fr;           // + m-terms
    const int brow0 = wc * 32 + fr;           // + j-terms

    auto STAGE_A = [&](int buf, int step, int half) {  // half0: lds 0-127, half1: 128-255
        const int aoff = step * 64;
        gld_lds16(aptr[2 * half]     + aoff, &At[buf][(2 * half)     * 4096 + tid * 8]);
        gld_lds16(aptr[2 * half + 1] + aoff, &At[buf][(2 * half + 1) * 4096 + tid * 8]);
    };
    auto STAGE_B = [&](int buf, int step, int half) {
        const int khw = step >> 2;
        const int kh  = (khw * 11) >> 5;      // khw/3
        const int kw  = khw - kh * 3;
        const int boff = (kh * PADW + kw) * 256 + (step & 3) * 64;
        gld_lds16(bptr[2 * half]     + boff, &Bt[buf][(2 * half)     * 4096 + tid * 8]);
        gld_lds16(bptr[2 * half + 1] + boff, &Bt[buf][(2 * half + 1) * 4096 + tid * 8]);
    };

    // prologue: stage tile 0 fully, drain once
    STAGE_A(0, 0, 0); STAGE_B(0, 0, 0); STAGE_B(0, 0, 1); STAGE_A(0, 0, 1);
    asm volatile("s_waitcnt vmcnt(0)" ::: "memory");
    __builtin_amdgcn_s_barrier();

    bf16x8 a[4][2], b[4][2];

    #define PH_BAR_IN  __builtin_amdgcn_s_barrier(); __builtin_amdgcn_s_setprio(1);
    #define PH_BAR_OUT __builtin_amdgcn_s_setprio(0); __builtin_amdgcn_s_barrier();
    #define MFMA_Q(mb, jb)                                                        \
        _Pragma("unroll")                                                         \
        for (int m = 0; m < 4; ++m)                                               \
            _Pragma("unroll")                                                     \
            for (int j = 0; j < 2; ++j) {                                         \
                acc[mb + m][jb + j] = __builtin_amdgcn_mfma_f32_16x16x32_bf16(    \
                    a[m][0], b[jb + j][0], acc[mb + m][jb + j], 0, 0, 0);         \
                acc[mb + m][jb + j] = __builtin_amdgcn_mfma_f32_16x16x32_bf16(    \
                    a[m][1], b[jb + j][1], acc[mb + m][jb + j], 0, 0, 0);         \
            }
    #define READ_A(mhalf)                                                         \
        _Pragma("unroll")                                                         \
        for (int m = 0; m < 4; ++m) {                                             \
            const int ar = (mhalf) * 128 + arow0 + 16 * m;                        \
            a[m][0] = *(const bf16x8*)(Ab + ar * 64 + so0);                       \
            a[m][1] = *(const bf16x8*)(Ab + ar * 64 + so1);                       \
        }
    #define READ_B(jb)                                                            \
        _Pragma("unroll")                                                         \
        for (int j = 0; j < 2; ++j) {                                             \
            const int br = ((jb + j) >> 1) * 128 + brow0 + ((jb + j) & 1) * 16;   \
            b[jb + j][0] = *(const bf16x8*)(Bb + br * 64 + so0);                  \
            b[jb + j][1] = *(const bf16x8*)(Bb + br * 64 + so1);                  \
        }
    #define VM6 asm volatile("s_waitcnt vmcnt(6)" ::: "memory");

    for (int t = 0; t < 35; ++t) {
        const int buf = t & 1;
        const int sb  = buf ^ 1;
        const __bf16* Ab = &At[buf][0];
        const __bf16* Bb = &Bt[buf][0];
        // q0: stage A-m03(t+1); read A m0-3 + B n01; MFMA m0-3 x n01
        STAGE_A(sb, t + 1, 0);
        VM6;
        READ_A(0); READ_B(0);
        PH_BAR_IN;  MFMA_Q(0, 0); PH_BAR_OUT;
        // q1: stage B-n01(t+1); read B n23; MFMA m0-3 x n23
        STAGE_B(sb, t + 1, 0);
        VM6;
        READ_B(2);
        PH_BAR_IN;  MFMA_Q(0, 2); PH_BAR_OUT;
        // q2: stage B-n23(t+1); read A m4-7; MFMA m4-7 x n01
        STAGE_B(sb, t + 1, 1);
        VM6;
        READ_A(1);
        PH_BAR_IN;  MFMA_Q(4, 0); PH_BAR_OUT;
        // q3: stage A-m47(t+1); MFMA m4-7 x n23
        STAGE_A(sb, t + 1, 1);
        VM6;
        PH_BAR_IN;  MFMA_Q(4, 2); PH_BAR_OUT;
    }
    // peeled tile 35 (buf 1): drain once, phases without stage/vmcnt
    {
        const __bf16* Ab = &At[1][0];
        const __bf16* Bb = &Bt[1][0];
        asm volatile("s_waitcnt vmcnt(0)" ::: "memory");
        READ_A(0); READ_B(0);
        PH_BAR_IN;  MFMA_Q(0, 0); PH_BAR_OUT;
        READ_B(2);
        PH_BAR_IN;  MFMA_Q(0, 2); PH_BAR_OUT;
        READ_A(1);
        PH_BAR_IN;  MFMA_Q(4, 0); PH_BAR_OUT;
        PH_BAR_IN;  MFMA_Q(4, 2); PH_BAR_OUT;
    }

    // epilogue: D col = lane&15 (pixel), row = (lane>>4)*4 + reg (cout)
    const int rbase = kg * 4;
    if (p0 + 64 * wc < HW) {                  // tail tile: only wave-col 0 valid
        #pragma unroll
        for (int m = 0; m < 8; ++m)
            #pragma unroll
            for (int j = 0; j < 4; ++j) {
                float* op = out + (size_t)(n * COUT_ + 128 * wr + m * 16 + rbase) * HW
                                + p0 + 64 * wc + j * 16 + fr;
                #pragma unroll
                for (int r = 0; r < 4; ++r)
                    op[(size_t)r * HW] = acc[m][j][r];
            }
    }
}

extern "C" void kernel_launch(void* const* d_in, const int* in_sizes, int n_in,
                              void* d_out, int out_size, void* d_ws, size_t ws_size,
                              hipStream_t stream) {
    const float* x      = (const float*)d_in[0];
    const float* weight = (const float*)d_in[1];
    const float* fc_w   = (const float*)d_in[2];
    const float* fc_b   = (const float*)d_in[3];
    float* out = (float*)d_out;

    // workspace layout (~92.9 MB)
    char* ws = (char*)d_ws;
    float* pooled = (float*)ws;                                   // 32 KB
    float* gate   = (float*)(ws + 32 * 1024);                     // 1 KB
    __bf16* wmix  = (__bf16*)(ws + 64 * 1024);                    // 37.75 MB
    __bf16* xTp   = (__bf16*)(ws + 64 * 1024 +
                              (size_t)NBATCH * COUT_ * KTOT * 2); // 55.1 MB

    init_kernel<<<dim3(512), 256, 0, stream>>>(xTp, pooled);
    transpose_kernel<<<dim3(49, 4, NBATCH), 256, 0, stream>>>(x, xTp, pooled);
    gate_kernel<<<dim3(1), 256, 0, stream>>>(pooled, fc_w, fc_b, gate);
    mix_kernel<<<dim3(COUT_, 4), 256, 0, stream>>>(weight, gate, wmix);
    conv_kernel<<<dim3(416), 512, 0, stream>>>(xTp, wmix, out);
}

// Round 12
// 183.575 us; speedup vs baseline: 1.1516x; 1.1516x over previous
//
#include <hip/hip_runtime.h>
#include <hip/hip_bf16.h>

#define E_    8
#define CIN_  256
#define COUT_ 256
#define NK    9
#define KTOT  2304      // CIN*9
#define IMGH  56
#define IMGW  56
#define HW    3136
#define NBATCH 32
#define PADW  58
#define PADHW 3364      // 58*58

typedef __attribute__((ext_vector_type(8))) __bf16 bf16x8;
typedef __attribute__((ext_vector_type(4))) float f32x4;
typedef unsigned int u32;

// async global->LDS, 16B per lane; LDS dest = wave-uniform base + lane*16
__device__ __forceinline__ void gld_lds16(const __bf16* g, __bf16* l) {
    __builtin_amdgcn_global_load_lds(
        (const __attribute__((address_space(1))) void*)(g),
        (__attribute__((address_space(3))) void*)(l), 16, 0, 0);
}

// ---- init: pooled = 0, xTp halo = 0 ----
__global__ __launch_bounds__(256) void init_kernel(__bf16* xTp, float* pooled) {
    const int tid0 = blockIdx.x * 256 + threadIdx.x;
    if (tid0 < NBATCH * CIN_) pooled[tid0] = 0.f;
    const int total = NBATCH * 228 * 128;     // halo u32 count
    u32* p = (u32*)xTp;
    for (int idx = tid0; idx < total; idx += gridDim.x * 256) {
        const int n  = idx / (228 * 128);
        const int r  = idx - n * (228 * 128);
        const int hp = r >> 7;
        const int cp = r & 127;
        int px;
        if (hp < 58)       px = hp;
        else if (hp < 116) px = 57 * PADW + (hp - 58);
        else if (hp < 172) px = (hp - 116 + 1) * PADW;
        else               px = (hp - 172 + 1) * PADW + 57;
        p[((size_t)(n * PADHW + px)) * 128 + cp] = 0u;
    }
}

// ---- transpose + pool ----
__global__ __launch_bounds__(256) void transpose_kernel(const float* __restrict__ x,
                                                        __bf16* __restrict__ xTp,
                                                        float* __restrict__ pooled) {
    __shared__ __bf16 t[64][66];
    const int px0 = blockIdx.x * 64;
    const int c0  = blockIdx.y * 64;
    const int n   = blockIdx.z;
    const int tid = threadIdx.x;
    {
        const int px_l = tid & 63;
        const int cb   = (tid >> 6) * 16;
        #pragma unroll
        for (int i = 0; i < 16; ++i) {
            const int cin_l = cb + i;
            t[cin_l][px_l] =
                (__bf16)x[((size_t)(n * CIN_ + c0 + cin_l)) * HW + px0 + px_l];
        }
    }
    __syncthreads();
    {
        const int cin_l = tid & 63;
        const int pb    = (tid >> 6) * 16;
        float s = 0.f;
        #pragma unroll
        for (int i = 0; i < 16; ++i) {
            const int px = px0 + pb + i;
            const int h  = px / IMGW;
            const int w  = px - h * IMGW;
            const __bf16 v = t[cin_l][pb + i];
            s += (float)v;
            xTp[((size_t)(n * PADHW + (h + 1) * PADW + (w + 1))) * CIN_ + c0 + cin_l] = v;
        }
        atomicAdd(&pooled[n * CIN_ + c0 + cin_l], s);
    }
}

// ---- mix (gate fused): block = (cout, n-chunk of 8); experts in registers --
__global__ __launch_bounds__(256) void mix_kernel(const float* __restrict__ weight,
                                                  const float* __restrict__ pooled,
                                                  const float* __restrict__ fc_w,
                                                  const float* __restrict__ fc_b,
                                                  __bf16* __restrict__ wmix) {
    __shared__ float wstage[KTOT];
    __shared__ __bf16 tlds[KTOT];
    __shared__ float gl[8][8];                // gate[n-local][e]
    const int cout = blockIdx.x;
    const int n0   = blockIdx.y * 8;
    const int tid  = threadIdx.x;
    // gate head: threads 0..63 each compute one (n-local, e) dot
    if (tid < 64) {
        const int nl = tid >> 3, e = tid & 7;
        const float* pv = pooled + (n0 + nl) * CIN_;
        const float* wv = fc_w + e * CIN_;
        float s = 0.f;
        for (int c = 0; c < CIN_; ++c) s += pv[c] * wv[c];
        s = s * (1.0f / HW) + fc_b[e];
        gl[nl][e] = 1.0f / (1.0f + expf(-s));
    }
    float wreg[E_][NK];
    for (int e = 0; e < E_; ++e) {
        const float* wp = weight + (size_t)(e * COUT_ + cout) * KTOT;
        #pragma unroll
        for (int i = 0; i < NK; ++i) wstage[tid + i * 256] = wp[tid + i * 256];
        __syncthreads();
        #pragma unroll
        for (int kk = 0; kk < NK; ++kk) wreg[e][kk] = wstage[tid * NK + kk];
        __syncthreads();
    }
    for (int n = n0; n < n0 + 8; ++n) {
        float g[E_];
        #pragma unroll
        for (int e = 0; e < E_; ++e) g[e] = gl[n - n0][e];
        float acc[NK];
        #pragma unroll
        for (int kk = 0; kk < NK; ++kk) acc[kk] = 0.f;
        #pragma unroll
        for (int e = 0; e < E_; ++e)
            #pragma unroll
            for (int kk = 0; kk < NK; ++kk) acc[kk] += g[e] * wreg[e][kk];
        #pragma unroll
        for (int kk = 0; kk < NK; ++kk) tlds[kk * 256 + tid] = (__bf16)acc[kk];
        __syncthreads();
        u32* dst = (u32*)(wmix + ((size_t)(n * COUT_ + cout)) * KTOT);
        const u32* src = (const u32*)tlds;
        #pragma unroll
        for (int j = 0; j < 4; ++j) dst[tid + j * 256] = src[tid + j * 256];
        if (tid < 128) dst[tid + 1024] = src[tid + 1024];
        __syncthreads();
    }
}

// ---------------- implicit-GEMM conv (r5/r10 structure, best measured) ----
// BM=256 couts x BN=224 pixels, 512 threads, 8 waves as 4M x 2N
// (wave tile 64x112 = 4x7 frags). 36 K-steps of 64, 2-buffer pipeline:
// STAGE(t+1) -> COMPUTE(t) -> __syncthreads (loads fly during compute,
// drain at the barrier). Proven 132 us / 37.5% MfmaUtil (r5, r10).
#define BM 256
#define BN 224

__global__ __launch_bounds__(512) void conv_kernel(const __bf16* __restrict__ xTp,
                                                   const __bf16* __restrict__ wmix,
                                                   float* __restrict__ out) {
    __shared__ __attribute__((aligned(16))) __bf16 At[2][BM * 64];  // 2x32 KB
    __shared__ __attribute__((aligned(16))) __bf16 Bt[2][BN * 64];  // 2x28 KB

    // bijective XCD swizzle (448 = 8*56); n-major within XCD for L2 locality
    const int bid = blockIdx.x;
    const int swz = (bid & 7) * 56 + (bid >> 3);
    const int n   = swz / 14;
    const int pt  = swz - n * 14;
    const int p0  = pt * BN;

    const int tid  = threadIdx.x;
    const int lane = tid & 63;
    const int wave = tid >> 6;
    const int lr   = lane >> 3;               // row-within-chunk 0..7
    const int sl   = lane & 7;                // 16B slot within 128B row
    const int swzsl = sl ^ lr;                // pre-swizzled source slot

    const __bf16* wmixn = wmix + (size_t)n * COUT_ * KTOT;
    const __bf16* xTpn  = xTp + (size_t)n * PADHW * CIN_;

    // A staging: chunk j = wave+8i covers cout rows 8j..8j+7
    const __bf16* asrc[4];
    #pragma unroll
    for (int i = 0; i < 4; ++i) {
        const int j = wave + 8 * i;
        asrc[i] = wmixn + (size_t)(8 * j + lr) * KTOT + swzsl * 8;
    }
    // B staging: chunk j = wave+8i (j<28) covers pixel rows 8j..8j+7
    const __bf16* bsrc[4];
    #pragma unroll
    for (int i = 0; i < 4; ++i) {
        int j = wave + 8 * i; if (j > 27) j = 27;   // clamped, never issued
        const int px = p0 + 8 * j + lr;
        const int h  = px / IMGW;
        const int w  = px - h * IMGW;
        bsrc[i] = xTpn + (size_t)(h * PADW + w) * CIN_ + swzsl * 8;
    }

    const f32x4 zero = {0.f, 0.f, 0.f, 0.f};
    f32x4 acc[4][7];
    #pragma unroll
    for (int i = 0; i < 4; ++i)
        #pragma unroll
        for (int j = 0; j < 7; ++j) acc[i][j] = zero;

    const int mbase = (wave >> 1) * 64;
    const int nbase = (wave & 1) * 112;
    const int fr = lane & 15;
    const int kg = lane >> 4;
    const int fswz = fr & 7;

    auto STAGE = [&](int buf, int stepk, int toff) {
        #pragma unroll
        for (int i = 0; i < 4; ++i)
            gld_lds16(asrc[i] + stepk * 64, &At[buf][(wave + 8 * i) * 512]);
        const int boff = toff * 256 + (stepk & 3) * 64;
        #pragma unroll
        for (int i = 0; i < 4; ++i)
            if (wave < 4 || i < 3)
                gld_lds16(bsrc[i] + boff, &Bt[buf][(wave + 8 * i) * 512]);
    };

    auto COMPUTE = [&](const __bf16* Ab, const __bf16* Bb) {
        #pragma unroll
        for (int ks = 0; ks < 2; ++ks) {
            const int soff = ((ks * 4 + kg) ^ fswz) * 8;
            bf16x8 a[4], b[7];
            #pragma unroll
            for (int m = 0; m < 4; ++m)
                a[m] = *(const bf16x8*)(Ab + (mbase + m * 16 + fr) * 64 + soff);
            #pragma unroll
            for (int nn = 0; nn < 7; ++nn)
                b[nn] = *(const bf16x8*)(Bb + (nbase + nn * 16 + fr) * 64 + soff);
            #pragma unroll
            for (int m = 0; m < 4; ++m)
                #pragma unroll
                for (int nn = 0; nn < 7; ++nn)
                    acc[m][nn] = __builtin_amdgcn_mfma_f32_16x16x32_bf16(
                        a[m], b[nn], acc[m][nn], 0, 0, 0);
        }
    };

    STAGE(0, 0, 0);
    __syncthreads();
    for (int khw = 0; khw < 9; ++khw) {
        const int kh  = (khw * 11) >> 5;          // khw/3
        const int kw  = khw - kh * 3;
        const int toff = kh * PADW + kw;
        const int kh2 = ((khw + 1) * 11) >> 5;    // (khw+1)/3
        const int kw2 = (khw + 1) - kh2 * 3;
        const int toff2 = kh2 * PADW + kw2;
        #pragma unroll
        for (int cb = 0; cb < 4; ++cb) {
            const int buf  = cb & 1;
            const int step = khw * 4 + cb;
            if (step < 35)
                STAGE(buf ^ 1, step + 1, (cb < 3) ? toff : toff2);
            COMPUTE(&At[buf][0], &Bt[buf][0]);
            __syncthreads();
        }
    }

    // epilogue: D col = lane&15 (pixel), row = (lane>>4)*4 + reg (cout)
    const int rbase = kg * 4;
    #pragma unroll
    for (int m = 0; m < 4; ++m)
        #pragma unroll
        for (int nn = 0; nn < 7; ++nn) {
            float* op = out + (size_t)(n * COUT_ + mbase + m * 16 + rbase) * HW
                            + p0 + nbase + nn * 16 + fr;
            #pragma unroll
            for (int r = 0; r < 4; ++r)
                op[(size_t)r * HW] = acc[m][nn][r];
        }
}

extern "C" void kernel_launch(void* const* d_in, const int* in_sizes, int n_in,
                              void* d_out, int out_size, void* d_ws, size_t ws_size,
                              hipStream_t stream) {
    const float* x      = (const float*)d_in[0];
    const float* weight = (const float*)d_in[1];
    const float* fc_w   = (const float*)d_in[2];
    const float* fc_b   = (const float*)d_in[3];
    float* out = (float*)d_out;

    // workspace layout (~92.9 MB)
    char* ws = (char*)d_ws;
    float* pooled = (float*)ws;                                   // 32 KB
    __bf16* wmix  = (__bf16*)(ws + 64 * 1024);                    // 37.75 MB
    __bf16* xTp   = (__bf16*)(ws + 64 * 1024 +
                              (size_t)NBATCH * COUT_ * KTOT * 2); // 55.1 MB

    init_kernel<<<dim3(512), 256, 0, stream>>>(xTp, pooled);
    transpose_kernel<<<dim3(49, 4, NBATCH), 256, 0, stream>>>(x, xTp, pooled);
    mix_kernel<<<dim3(COUT_, 4), 256, 0, stream>>>(weight, pooled, fc_w, fc_b, wmix);
    conv_kernel<<<dim3(448), 512, 0, stream>>>(xTp, wmix, out);
}